// Round 2
// baseline (2334.448 us; speedup 1.0000x reference)
//
#include <hip/hip_runtime.h>

using bf16x8 = __attribute__((ext_vector_type(8))) __bf16;
using f32x4  = __attribute__((ext_vector_type(4))) float;

__device__ __forceinline__ unsigned short f2bf(float f){
  unsigned int u = __float_as_uint(f);
  u += 0x7fffu + ((u >> 16) & 1u);     // round-to-nearest-even
  return (unsigned short)(u >> 16);
}
__device__ __forceinline__ float bf2f(unsigned short h){
  return __uint_as_float(((unsigned int)h) << 16);
}

// ---------------- weight fp32 -> bf16 convert ----------------
__global__ __launch_bounds__(256) void cvt_bf16(const float* __restrict__ s,
                                                unsigned short* __restrict__ d, int n){
  int i = blockIdx.x * 256 + threadIdx.x;
  if (i < n) d[i] = f2bf(s[i]);
}

// ---------------- front (amp): h = gelu(LN(x@aW1.T + b1)) ----------------
// one block (256 thr) per batch row; 4096 outputs (16/thr)
__global__ __launch_bounds__(256) void front_amp_kernel(
    const float* __restrict__ x,
    const float* __restrict__ W1, const float* __restrict__ b1,
    const float* __restrict__ g1, const float* __restrict__ be1,
    unsigned short* __restrict__ h)
{
  __shared__ float red[256];
  __shared__ float red2[256];
  __shared__ float s_mean, s_inv;
  const int row = blockIdx.x;
  const int tid = threadIdx.x;
  const float x0 = x[row * 2 + 0];
  const float x1 = x[row * 2 + 1];

  float va[16];
  float sum = 0.f, sq = 0.f;
#pragma unroll
  for (int i = 0; i < 16; i++){
    int j = i * 256 + tid;
    float v = x0 * W1[2 * j] + x1 * W1[2 * j + 1] + b1[j];
    va[i] = v; sum += v; sq += v * v;
  }
  red[tid] = sum; red2[tid] = sq; __syncthreads();
  for (int s = 128; s > 0; s >>= 1){
    if (tid < s){ red[tid] += red[tid + s]; red2[tid] += red2[tid + s]; }
    __syncthreads();
  }
  if (tid == 0){
    float m = red[0] * (1.0f / 4096.0f);
    float v = red2[0] * (1.0f / 4096.0f) - m * m;
    s_mean = m; s_inv = rsqrtf(v + 1e-5f);
  }
  __syncthreads();
  float mean = s_mean, inv = s_inv;
#pragma unroll
  for (int i = 0; i < 16; i++){
    int j = i * 256 + tid;
    float y = (va[i] - mean) * inv * g1[j] + be1[j];
    float ge = 0.5f * y * (1.0f + erff(y * 0.70710678118654752f));
    h[(size_t)row * 4096 + j] = f2bf(ge);
  }
}

// ---------------- front (phase): p = silu(LN(x@pW1.T + b1)) ----------------
// 2048 outputs (8/thr)
__global__ __launch_bounds__(256) void front_ph_kernel(
    const float* __restrict__ x,
    const float* __restrict__ W1, const float* __restrict__ b1,
    const float* __restrict__ g1, const float* __restrict__ be1,
    unsigned short* __restrict__ p)
{
  __shared__ float red[256];
  __shared__ float red2[256];
  __shared__ float s_mean, s_inv;
  const int row = blockIdx.x;
  const int tid = threadIdx.x;
  const float x0 = x[row * 2 + 0];
  const float x1 = x[row * 2 + 1];

  float vp[8];
  float sum = 0.f, sq = 0.f;
#pragma unroll
  for (int i = 0; i < 8; i++){
    int j = i * 256 + tid;
    float v = x0 * W1[2 * j] + x1 * W1[2 * j + 1] + b1[j];
    vp[i] = v; sum += v; sq += v * v;
  }
  red[tid] = sum; red2[tid] = sq; __syncthreads();
  for (int s = 128; s > 0; s >>= 1){
    if (tid < s){ red[tid] += red[tid + s]; red2[tid] += red2[tid + s]; }
    __syncthreads();
  }
  if (tid == 0){
    float m = red[0] * (1.0f / 2048.0f);
    float v = red2[0] * (1.0f / 2048.0f) - m * m;
    s_mean = m; s_inv = rsqrtf(v + 1e-5f);
  }
  __syncthreads();
  float mean = s_mean, inv = s_inv;
#pragma unroll
  for (int i = 0; i < 8; i++){
    int j = i * 256 + tid;
    float y = (vp[i] - mean) * inv * g1[j] + be1[j];
    float si = y / (1.0f + expf(-y));
    p[(size_t)row * 2048 + j] = f2bf(si);
  }
}

// ---------------- row-wise LN + tanh, in place on bf16 (N=2048) ----------------
__global__ __launch_bounds__(256) void ln_tanh_kernel(
    unsigned short* __restrict__ c, const float* __restrict__ g,
    const float* __restrict__ be)
{
  __shared__ float red[256];
  __shared__ float red2[256];
  __shared__ float s_mean, s_inv;
  const size_t base = (size_t)blockIdx.x * 2048;
  const int tid = threadIdx.x;
  float v[8];
  float sum = 0.f, sq = 0.f;
#pragma unroll
  for (int i = 0; i < 8; i++){
    int j = i * 256 + tid;
    float t = bf2f(c[base + j]);
    v[i] = t; sum += t; sq += t * t;
  }
  red[tid] = sum; red2[tid] = sq; __syncthreads();
  for (int s = 128; s > 0; s >>= 1){
    if (tid < s){ red[tid] += red[tid + s]; red2[tid] += red2[tid + s]; }
    __syncthreads();
  }
  if (tid == 0){
    float m = red[0] * (1.0f / 2048.0f);
    float vv = red2[0] * (1.0f / 2048.0f) - m * m;
    s_mean = m; s_inv = rsqrtf(vv + 1e-5f);
  }
  __syncthreads();
  float mean = s_mean, inv = s_inv;
#pragma unroll
  for (int i = 0; i < 8; i++){
    int j = i * 256 + tid;
    float y = (v[i] - mean) * inv * g[j] + be[j];
    c[base + j] = f2bf(tanhf(y));
  }
}

// ---------------- bf16 MFMA GEMM: C = A @ B^T (+epilogue) ----------------
// A: [M][K] bf16, B: [N][K] bf16 (both K contiguous). 128x128 tile, BK=32.
// 256 thr = 4 waves in 2x2; each wave 64x64 = 4x4 tiles of 16x16x32 MFMA.
// EPI: 0 = bf16(val + bias[col])
//      1 = bf16((sin((val+bias)*rf0+rp0) + ry + tanh(rp2))/3)  [amp+combine; aux2=ry]
//      2 = bf16(cos(tanh(val+bias)*rf1 + rp1))                 [phase ry]
//      3 = f32(val + bias[col])                                [final]
template<int EPI>
__global__ __launch_bounds__(256) void gemm_bt(
    const unsigned short* __restrict__ A, const unsigned short* __restrict__ B,
    void* __restrict__ outp, int M, int N, int K,
    const float* __restrict__ bias,
    const float* __restrict__ aux0, const float* __restrict__ aux1,
    const unsigned short* __restrict__ aux2)
{
  constexpr int LDK = 32 + 8;                 // padded LDS row stride (halves)
  __shared__ unsigned short sA[128 * LDK];
  __shared__ unsigned short sB[128 * LDK];

  const int tid  = threadIdx.x;
  const int wave = tid >> 6, lane = tid & 63;
  const int wm = wave >> 1, wn = wave & 1;
  const int lm = lane & 15, lq = lane >> 4;
  const int m0 = blockIdx.y * 128, n0 = blockIdx.x * 128;

  f32x4 acc[4][4];
#pragma unroll
  for (int i = 0; i < 4; i++)
#pragma unroll
    for (int j = 0; j < 4; j++) acc[i][j] = (f32x4){0.f, 0.f, 0.f, 0.f};

  const int r0 = tid >> 2;            // 0..63
  const int c0 = (tid & 3) * 8;       // 0,8,16,24

  for (int k0 = 0; k0 < K; k0 += 32){
    __syncthreads();
    *(bf16x8*)&sA[r0 * LDK + c0]        = *(const bf16x8*)&A[(size_t)(m0 + r0) * K + k0 + c0];
    *(bf16x8*)&sA[(r0 + 64) * LDK + c0] = *(const bf16x8*)&A[(size_t)(m0 + r0 + 64) * K + k0 + c0];
    *(bf16x8*)&sB[r0 * LDK + c0]        = *(const bf16x8*)&B[(size_t)(n0 + r0) * K + k0 + c0];
    *(bf16x8*)&sB[(r0 + 64) * LDK + c0] = *(const bf16x8*)&B[(size_t)(n0 + r0 + 64) * K + k0 + c0];
    __syncthreads();

    bf16x8 af[4], bfr[4];
#pragma unroll
    for (int t = 0; t < 4; t++)
      af[t]  = *(const bf16x8*)&sA[(wm * 64 + t * 16 + lm) * LDK + lq * 8];
#pragma unroll
    for (int t = 0; t < 4; t++)
      bfr[t] = *(const bf16x8*)&sB[(wn * 64 + t * 16 + lm) * LDK + lq * 8];
#pragma unroll
    for (int i = 0; i < 4; i++)
#pragma unroll
      for (int j = 0; j < 4; j++)
        acc[i][j] = __builtin_amdgcn_mfma_f32_16x16x32_bf16(af[i], bfr[j], acc[i][j], 0, 0, 0);
  }

  // epilogue: C/D layout col=lane&15, row=(lane>>4)*4+reg
#pragma unroll
  for (int i = 0; i < 4; i++){
    const int rbase = m0 + wm * 64 + i * 16 + lq * 4;
#pragma unroll
    for (int j = 0; j < 4; j++){
      const int col = n0 + wn * 64 + j * 16 + lm;
#pragma unroll
      for (int r = 0; r < 4; r++){
        const int row = rbase + r;
        const float val = acc[i][j][r];
        const size_t idx = (size_t)row * N + col;
        if constexpr (EPI == 0){
          ((unsigned short*)outp)[idx] = f2bf(val + bias[col]);
        } else if constexpr (EPI == 1){
          float a  = val + bias[col];
          float rx = sinf(a * aux0[3 * col] + aux1[3 * col]);
          float rz = tanhf(aux1[3 * col + 2]);
          float ry = bf2f(aux2[idx]);
          ((unsigned short*)outp)[idx] = f2bf((rx + ry + rz) * (1.0f / 3.0f));
        } else if constexpr (EPI == 2){
          float t  = tanhf(val + bias[col]);
          ((unsigned short*)outp)[idx] = f2bf(cosf(t * aux0[3 * col + 1] + aux1[3 * col + 1]));
        } else {
          ((float*)outp)[idx] = val + bias[col];
        }
      }
    }
  }
}

extern "C" void kernel_launch(void* const* d_in, const int* in_sizes, int n_in,
                              void* d_out, int out_size, void* d_ws, size_t ws_size,
                              hipStream_t stream)
{
  const float* x    = (const float*)d_in[0];
  const float* aW1  = (const float*)d_in[1];
  const float* ab1  = (const float*)d_in[2];
  const float* ag1  = (const float*)d_in[3];
  const float* abe1 = (const float*)d_in[4];
  const float* aW2  = (const float*)d_in[5];
  const float* ab2  = (const float*)d_in[6];
  const float* ag2  = (const float*)d_in[7];
  const float* abe2 = (const float*)d_in[8];
  const float* aW3  = (const float*)d_in[9];
  const float* ab3  = (const float*)d_in[10];
  const float* pW1  = (const float*)d_in[11];
  const float* pb1  = (const float*)d_in[12];
  const float* pg1  = (const float*)d_in[13];
  const float* pbe1 = (const float*)d_in[14];
  const float* pW2  = (const float*)d_in[15];
  const float* pb2  = (const float*)d_in[16];
  const float* rfreq  = (const float*)d_in[17];
  const float* rphase = (const float*)d_in[18];
  const float* aiw  = (const float*)d_in[19];
  const float* aib  = (const float*)d_in[20];
  const float* aow  = (const float*)d_in[21];
  const float* aob  = (const float*)d_in[22];

  const int B = 16384, Q = 1024;

  // ---- workspace layout (~188 MB; c2 lives in d_out) ----
  char* ws = (char*)d_ws;
  size_t off = 0;
  auto alloc = [&](size_t bytes) -> char* {
    char* ptr = ws + off; off += (bytes + 255) & ~(size_t)255; return ptr;
  };
  unsigned short* Wb2  = (unsigned short*)alloc((size_t)2 * Q * 4 * Q * 2); // 16 MB
  unsigned short* Wb3  = (unsigned short*)alloc((size_t)Q * 2 * Q * 2);     //  4 MB
  unsigned short* PWb2 = (unsigned short*)alloc((size_t)Q * 2 * Q * 2);     //  4 MB
  unsigned short* WVb  = (unsigned short*)alloc((size_t)Q * Q * 2);         //  2 MB
  unsigned short* WOb  = (unsigned short*)alloc((size_t)Q * Q * 2);         //  2 MB
  unsigned short* R1   = (unsigned short*)alloc((size_t)B * 4 * Q * 2);     // 128 MB shared region
  unsigned short* ry   = (unsigned short*)alloc((size_t)B * Q * 2);         //  32 MB

  // R1 overlays (time-disjoint):
  unsigned short* p  = R1;                      // phase act (dead after gemm_ph)
  unsigned short* h  = R1;                      // amp act   (dead after gemm1)
  unsigned short* qs = R1;                      // combine out (after h dead)
  unsigned short* v  = R1 + (size_t)B * Q;      // v (after h dead)
  unsigned short* c2 = (unsigned short*)d_out;  // borrow output buffer (64 MB), dead before final GEMM

  // weight converts (bf16)
  cvt_bf16<<<(2*Q*4*Q + 255) / 256, 256, 0, stream>>>(aW2, Wb2, 2*Q*4*Q);
  cvt_bf16<<<(Q*2*Q + 255) / 256, 256, 0, stream>>>(aW3, Wb3, Q*2*Q);
  cvt_bf16<<<(Q*2*Q + 255) / 256, 256, 0, stream>>>(pW2, PWb2, Q*2*Q);
  cvt_bf16<<<(Q*Q + 255) / 256, 256, 0, stream>>>(aiw + (size_t)2*Q*Q, WVb, Q*Q);
  cvt_bf16<<<(Q*Q + 255) / 256, 256, 0, stream>>>(aow, WOb, Q*Q);

  const float* rf4 = rfreq  + (size_t)4 * Q * 3;   // rot_freq[-1]
  const float* rp4 = rphase + (size_t)4 * Q * 3;   // rot_phase[-1]

  // ---- phase path first (so p's region can be reused by h) ----
  front_ph_kernel<<<B, 256, 0, stream>>>(x, pW1, pb1, pg1, pbe1, p);
  // ry = cos(tanh(p@pW2.T + pb2)*rf1 + rp1)   (N=1024, K=2048)
  gemm_bt<2><<<dim3(Q/128, B/128), 256, 0, stream>>>(p, PWb2, ry, B, Q, 2*Q,
                                                     pb2, rf4, rp4, nullptr);

  // ---- amp path ----
  front_amp_kernel<<<B, 256, 0, stream>>>(x, aW1, ab1, ag1, abe1, h);
  // GEMM1: c2 = h @ aW2.T + b2   (M=16384, N=2048, K=4096), bf16 out (in d_out)
  gemm_bt<0><<<dim3(2*Q/128, B/128), 256, 0, stream>>>(h, Wb2, c2, B, 2*Q, 4*Q,
                                                       ab2, nullptr, nullptr, nullptr);
  // h2 = tanh(LN(c2)) in place
  ln_tanh_kernel<<<B, 256, 0, stream>>>(c2, ag2, abe2);

  // GEMM2 (fused combine): qs = (sin((c2h@aW3.T+b3)*rf0+rp0) + ry + tanh(rp2))/3
  gemm_bt<1><<<dim3(Q/128, B/128), 256, 0, stream>>>(c2, Wb3, qs, B, Q, 2*Q,
                                                     ab3, rf4, rp4, ry);
  // GEMM4: v = qs @ aiw[2Q:].T + aib[2Q:]   (N=1024, K=1024)
  gemm_bt<0><<<dim3(Q/128, B/128), 256, 0, stream>>>(qs, WVb, v, B, Q, Q,
                                                     aib + 2*Q, nullptr, nullptr, nullptr);
  // GEMM5: out = v @ aow.T + aob   (N=1024, K=1024), fp32 out (overwrites dead c2)
  gemm_bt<3><<<dim3(Q/128, B/128), 256, 0, stream>>>(v, WOb, d_out, B, Q, Q,
                                                     aob, nullptr, nullptr, nullptr);
}